// Round 9
// baseline (1696.237 us; speedup 1.0000x reference)
//
#include <hip/hip_runtime.h>

// GRU, producer-consumer fused with 256-slot gi ring (fits ws ~411 MB):
//   A) f32->bf16 converts.
//   B) gru_fused, grid 256 x 512, 1 block/CU (LDS-forced):
//      blocks 0-31   consumers: R3/R7-proven recurrence, 512 steps, 4-deep LDS ring,
//                    counted vmcnt, 1 barrier/step; waits item flags; publishes
//                    slots_read progress every 16 steps (fetch_max RMW).
//      blocks 32-255 producers: gi tiles via MFMA from emb16/Wih16 (item = 4 t x one
//                    16-batch tile), swizzled LDS image -> linear store into ring slot
//                    (t & 255); waits consumer progress before gen-2 overwrite;
//                    release fetch_or flag per item (L2 writeback -> IC visible).

typedef unsigned short ushort_t;
typedef __attribute__((ext_vector_type(8))) short short8;
typedef __attribute__((ext_vector_type(4))) float float4_;
typedef __attribute__((ext_vector_type(4))) unsigned short ushort4_;
typedef __attribute__((ext_vector_type(2))) unsigned int uint2_;
typedef __attribute__((ext_vector_type(4))) int int4_;

#define VOCAB 32000
#define EMB 128
#define HID 256
#define G3 768
#define TT 512
#define SLOT 786432        // gi bytes per timestep
#define BLK_BYTES 24576    // gi bytes per (t, 16-batch blk)
#define RING_T 256         // ring timesteps (201,326,592 B)
#define FLAGS_OFF 8781824  // 512 B item flags
#define PROG_OFF 8782336   // 32 x int consumer progress
#define GI_OFF 8785920     // ring start; end = 210,112,512
#define NPROD 224
#define NITEM 4096         // 128 tq * 32 blk

__device__ __forceinline__ float b2f(ushort_t u) {
  return __uint_as_float(((unsigned)u) << 16);
}
__device__ __forceinline__ ushort_t f2b(float f) {
  unsigned u = __float_as_uint(f);
  return (ushort_t)((u + 0x7FFFu + ((u >> 16) & 1u)) >> 16);
}
__device__ __forceinline__ short8 ld8(const ushort_t* p) { return *(const short8*)p; }
__device__ __forceinline__ void gld_lds16(const void* g, void* l) {
  __builtin_amdgcn_global_load_lds((const __attribute__((address_space(1))) void*)g,
                                   (__attribute__((address_space(3))) void*)l, 16, 0, 0);
}
__device__ __forceinline__ int gi_byte(int bl, int c) {
  return ((bl * 1536) + c) ^ ((bl & 7) << 4);
}
__device__ __forceinline__ void wait_item(const unsigned* flags, int item) {
  const unsigned bit = 1u << (item & 31);
  const unsigned* wp = flags + (item >> 5);
  while (!(__hip_atomic_load(wp, __ATOMIC_RELAXED, __HIP_MEMORY_SCOPE_AGENT) & bit))
    __builtin_amdgcn_s_sleep(8);
  __builtin_amdgcn_fence(__ATOMIC_ACQUIRE, "agent");
}

// ---------------- Phase A ----------------
__global__ void cvt_bf16_k(const float* __restrict__ s, ushort_t* __restrict__ d, int n4) {
  int i = blockIdx.x * blockDim.x + threadIdx.x;
  int stride = gridDim.x * blockDim.x;
  for (; i < n4; i += stride) {
    float4_ v = ((const float4_*)s)[i];
    ushort4_ o;
    o.x = f2b(v.x); o.y = f2b(v.y); o.z = f2b(v.z); o.w = f2b(v.w);
    ((ushort4_*)d)[i] = o;
  }
}

// ---------------- Phase B: fused producer/consumer ----------------
// LDS (consumer): ring[4][24576] @0 | h[2][8192] @98304             = 114688
// LDS (producer): img[4][24576] @0 | xe[64][256] @98304 | cb @114688 = 117760
__global__ __launch_bounds__(512, 1) void gru_fused(
    const int* __restrict__ x, const ushort_t* __restrict__ emb16,
    const ushort_t* __restrict__ Wih16, const ushort_t* __restrict__ Whh16,
    const float* __restrict__ bih, const float* __restrict__ bhh,
    char* __restrict__ gi, unsigned* __restrict__ flags,
    int* __restrict__ progress, float* __restrict__ out) {
  __shared__ alignas(16) char smem[117760];
  const int tid = threadIdx.x, lane = tid & 63, w = tid >> 6;
  const int bl = lane & 15, kg = lane >> 4;
  const int s16 = (bl & 7) << 4;

  if (blockIdx.x >= 32) {
    // ================= PRODUCER =================
    const int pid = blockIdx.x - 32;
    char* img = smem;
    char* xe = smem + 98304;
    float* cb = (float*)(smem + 114688);
    for (int i = tid; i < G3; i += 512) cb[i] = bih[i] + (i < 512 ? bhh[i] : 0.f);
    __syncthreads();

#pragma unroll 1
    for (int it = pid; it < NITEM; it += NPROD) {
      const int tq = it >> 5, blk = it & 31, t0 = tq * 4;
      // stage xe: 64 rows (4t x 16b) of emb16, source-XOR, linear dest
#pragma unroll
      for (int gg = 0; gg < 2; ++gg) {
        int g = 2 * w + gg;
        int row = g * 4 + (lane >> 4);
        int tok = x[(blk * 16 + (row & 15)) * TT + t0 + (row >> 4)];
        const char* src = (const char*)emb16 + (size_t)((unsigned)tok) * 256u +
                          ((((unsigned)lane & 15u) << 4) ^ (((unsigned)row & 15u) << 4));
        gld_lds16(src, xe + g * 1024);
      }
      asm volatile("s_waitcnt vmcnt(0)" ::: "memory");
      __syncthreads();
      short8 bfr[4][4];
#pragma unroll
      for (int t = 0; t < 4; ++t)
#pragma unroll
        for (int kt = 0; kt < 4; ++kt)
          bfr[t][kt] = *(const short8*)(xe + (t * 16 + bl) * 256 +
                                        ((kt * 64 + kg * 16) ^ (bl << 4)));
#pragma unroll 1
      for (int mi = 0; mi < 6; ++mi) {
        int mt = w * 6 + mi;
        short8 af[4];
#pragma unroll
        for (int kt = 0; kt < 4; ++kt)
          af[kt] = ld8(Wih16 + (mt * 16 + bl) * EMB + kt * 32 + kg * 8);
        float4_ z4 = {0.f, 0.f, 0.f, 0.f};
        float4_ acc[4] = {z4, z4, z4, z4};
#pragma unroll
        for (int kt = 0; kt < 4; ++kt)
#pragma unroll
          for (int t = 0; t < 4; ++t)
            acc[t] = __builtin_amdgcn_mfma_f32_16x16x32_bf16(af[kt], bfr[t][kt], acc[t], 0, 0, 0);
        float4_ cbv = *(const float4_*)(cb + mt * 16 + kg * 4);
        int db = (bl * 1536 + 32 * mt + 8 * kg) ^ s16;
#pragma unroll
        for (int t = 0; t < 4; ++t) {
          ushort4_ o;
#pragma unroll
          for (int r = 0; r < 4; ++r) o[r] = f2b(acc[t][r] + cbv[r]);
          *(ushort4_*)(img + t * 24576 + db) = o;
        }
      }
      __syncthreads();
      // ring-overwrite guard: gen-2 slots need consumer to have read gen-1
      if (tq >= 64) {
        int need = 4 * tq - 252;
        while (__hip_atomic_load(&progress[blk], __ATOMIC_RELAXED,
                                 __HIP_MEMORY_SCOPE_AGENT) < need)
          __builtin_amdgcn_s_sleep(16);
        __builtin_amdgcn_fence(__ATOMIC_ACQUIRE, "agent");
      }
      // linear coalesced store into ring slot (4tq & 255)
      char* dstb = gi + (size_t)(t0 & (RING_T - 1)) * SLOT + (size_t)blk * BLK_BYTES;
#pragma unroll
      for (int t = 0; t < 4; ++t)
#pragma unroll
        for (int ii = 0; ii < 3; ++ii) {
          float4_ v = *(const float4_*)(img + t * 24576 + tid * 48 + ii * 16);
          *(float4_*)(dstb + (size_t)t * SLOT + tid * 48 + ii * 16) = v;
        }
      asm volatile("s_waitcnt vmcnt(0)" ::: "memory");
      __syncthreads();
      if (tid == 0)
        __hip_atomic_fetch_or(&flags[it >> 5], 1u << (it & 31),
                              __ATOMIC_RELEASE, __HIP_MEMORY_SCOPE_AGENT);
    }
    return;
  }

  // ================= CONSUMER (R3/R7-proven body) =================
  const int bx = blockIdx.x;
  const int b0 = bx * 16;

  {
    int4_ z4 = {0, 0, 0, 0};
    *(int4_*)(smem + 98304 + tid * 16) = z4;  // zero h[0]
  }
  __syncthreads();

  short8 wf[2][3][8];
#pragma unroll
  for (int i = 0; i < 2; ++i)
#pragma unroll
    for (int q = 0; q < 3; ++q) {
      int g = (w + 8 * i + 16 * q) * 16 + bl;
#pragma unroll
      for (int kt = 0; kt < 8; ++kt)
        wf[i][q][kt] = ld8(Whh16 + (size_t)g * HID + kt * 32 + kg * 8);
    }

  float4_ bhn[2];
  float hreg[2][4];
#pragma unroll
  for (int i = 0; i < 2; ++i) {
    bhn[i] = *(const float4_*)&bhh[512 + (w + 8 * i) * 16 + kg * 4];
#pragma unroll
    for (int r = 0; r < 4; ++r) hreg[i][r] = 0.f;
  }

  asm volatile("s_waitcnt vmcnt(0) lgkmcnt(0)" ::: "memory");
  __builtin_amdgcn_s_barrier();
  __builtin_amdgcn_sched_barrier(0);

  // prologue: item (tq=0, bx) covers t=0..3 -> stage ring slots 0..2
  wait_item(flags, bx);
#pragma unroll
  for (int tau = 0; tau < 3; ++tau) {
    const char* src = gi + (size_t)tau * SLOT + (size_t)bx * BLK_BYTES + (w * 3) * 1024 + lane * 16;
    char* dst = smem + tau * 24576 + (w * 3) * 1024;
#pragma unroll
    for (int ii = 0; ii < 3; ++ii) gld_lds16(src + ii * 1024, dst + ii * 1024);
  }

#pragma unroll 1
  for (int t = 0; t < TT; ++t) {
    int rem = TT - 1 - t;
    if (rem >= 2)
      asm volatile("s_waitcnt vmcnt(6) lgkmcnt(0)" ::: "memory");
    else if (rem == 1)
      asm volatile("s_waitcnt vmcnt(3) lgkmcnt(0)" ::: "memory");
    else
      asm volatile("s_waitcnt vmcnt(0) lgkmcnt(0)" ::: "memory");
    __builtin_amdgcn_s_barrier();
    __builtin_amdgcn_sched_barrier(0);

    // publish slots_read = t+1 (gi reads for slots <= t completed by the vmcnt above)
    if (((t & 15) == 0) && tid == 0)
      __hip_atomic_fetch_max(&progress[bx], t + 1, __ATOMIC_RELAXED,
                             __HIP_MEMORY_SCOPE_AGENT);

    const int slot = t & 3, cur = t & 1, nxt = cur ^ 1;
    if (t + 3 < TT) {
      if (((t + 3) & 3) == 0) wait_item(flags, ((t + 3) >> 2) * 32 + bx);
      const char* src = gi + (size_t)((t + 3) & (RING_T - 1)) * SLOT +
                        (size_t)bx * BLK_BYTES + (w * 3) * 1024 + lane * 16;
      char* dst = smem + ((t + 3) & 3) * 24576 + (w * 3) * 1024;
#pragma unroll
      for (int ii = 0; ii < 3; ++ii) gld_lds16(src + ii * 1024, dst + ii * 1024);
    }

    const char* gtile = smem + slot * 24576;

    float4_ acc[2][3];
#pragma unroll
    for (int i = 0; i < 2; ++i) {
#pragma unroll
      for (int q = 0; q < 2; ++q) {
        int byte8 = gi_byte(bl, 32 * (w + 8 * i + 16 * q) + 8 * kg);
        ushort4_ v = *(const ushort4_*)(gtile + byte8);
#pragma unroll
        for (int r = 0; r < 4; ++r) acc[i][q][r] = b2f(v[r]);
      }
      acc[i][2] = bhn[i];
    }

#pragma unroll
    for (int kt = 0; kt < 8; ++kt) {
      int byteoff = ((bl * 512) + kt * 64 + kg * 16) ^ s16;
      short8 bf = *(const short8*)(smem + 98304 + cur * 8192 + byteoff);
#pragma unroll
      for (int i = 0; i < 2; ++i)
#pragma unroll
        for (int q = 0; q < 3; ++q)
          acc[i][q] = __builtin_amdgcn_mfma_f32_16x16x32_bf16(wf[i][q][kt], bf, acc[i][q], 0, 0, 0);
    }

#pragma unroll
    for (int i = 0; i < 2; ++i) {
      int byte8n = gi_byte(bl, 32 * (32 + w + 8 * i) + 8 * kg);
      ushort4_ gv = *(const ushort4_*)(gtile + byte8n);
#pragma unroll
      for (int r = 0; r < 4; ++r) {
        float rr = __builtin_amdgcn_rcpf(1.f + __expf(-acc[i][0][r]));
        float zz = __builtin_amdgcn_rcpf(1.f + __expf(-acc[i][1][r]));
        float y = b2f(gv[r]) + rr * acc[i][2][r];
        float nn = 1.f - 2.f * __builtin_amdgcn_rcpf(1.f + __expf(2.f * y));
        hreg[i][r] = (1.f - zz) * nn + zz * hreg[i][r];
      }
      int byte0 = (bl * 512 + ((w + 8 * i) * 16 + kg * 4) * 2) ^ s16;
      uint2_ hv;
      hv.x = (unsigned)f2b(hreg[i][0]) | ((unsigned)f2b(hreg[i][1]) << 16);
      hv.y = (unsigned)f2b(hreg[i][2]) | ((unsigned)f2b(hreg[i][3]) << 16);
      *(uint2_*)(smem + 98304 + nxt * 8192 + byte0) = hv;
    }
  }

#pragma unroll
  for (int i = 0; i < 2; ++i) {
    float4_ v = {hreg[i][0], hreg[i][1], hreg[i][2], hreg[i][3]};
    *(float4_*)&out[(size_t)(b0 + bl) * HID + (w + 8 * i) * 16 + kg * 4] = v;
  }
}

extern "C" void kernel_launch(void* const* d_in, const int* in_sizes, int n_in,
                              void* d_out, int out_size, void* d_ws, size_t ws_size,
                              hipStream_t stream) {
  const int* x = (const int*)d_in[0];
  const float* emb = (const float*)d_in[1];
  const float* Wih = (const float*)d_in[2];
  const float* Whh = (const float*)d_in[3];
  const float* bih = (const float*)d_in[4];
  const float* bhh = (const float*)d_in[5];
  float* out = (float*)d_out;

  char* ws = (char*)d_ws;
  ushort_t* emb16 = (ushort_t*)ws;                 // 8,192,000 B
  ushort_t* Wih16 = (ushort_t*)(ws + 8192000);     //   196,608 B
  ushort_t* Whh16 = (ushort_t*)(ws + 8388608);     //   393,216 B
  unsigned* flags = (unsigned*)(ws + FLAGS_OFF);   //       512 B
  int* progress = (int*)(ws + PROG_OFF);           //       128 B
  char* gi = ws + GI_OFF;                          // 201,326,592 B ring

  cvt_bf16_k<<<1024, 256, 0, stream>>>(emb, emb16, (VOCAB * EMB) / 4);
  cvt_bf16_k<<<96, 256, 0, stream>>>(Wih, Wih16, (G3 * EMB) / 4);
  cvt_bf16_k<<<192, 256, 0, stream>>>(Whh, Whh16, (G3 * HID) / 4);
  hipMemsetAsync(ws + FLAGS_OFF, 0, 1024, stream);
  gru_fused<<<256, 512, 0, stream>>>(x, emb16, Wih16, Whh16, bih, bhh, gi, flags, progress, out);
}

// Round 10
// 1508.722 us; speedup vs baseline: 1.1243x; 1.1243x over previous
//
#include <hip/hip_runtime.h>

// GRU, producer-consumer fused, TWO launches of 256 steps (write-once gi per launch):
//   A) f32->bf16 converts.
//   B) gru_fused(phase), grid 256 x 512, 1 block/CU (LDS-forced):
//      blocks 0-31   consumers: R7-proven recurrence, 256 steps, 4-deep LDS ring,
//                    counted vmcnt, 1 barrier/step; tid0-gated flag wait per item
//                    (4 steps), NO fences (write-once + dispatch acquire).
//      blocks 32-255 producers: 2048 items (4t x 16-batch tile) via MFMA from
//                    emb16/Wih16; swizzled LDS image -> linear store; release
//                    fetch_or flag. No polling anywhere on the producer side.
//   h crosses the launch boundary via d_out (f32, exact).

typedef unsigned short ushort_t;
typedef __attribute__((ext_vector_type(8))) short short8;
typedef __attribute__((ext_vector_type(4))) float float4_;
typedef __attribute__((ext_vector_type(4))) unsigned short ushort4_;
typedef __attribute__((ext_vector_type(2))) unsigned int uint2_;
typedef __attribute__((ext_vector_type(4))) int int4_;

#define VOCAB 32000
#define EMB 128
#define HID 256
#define G3 768
#define TT 512
#define CSTEPS 256         // steps per launch
#define SLOT 786432        // gi bytes per timestep
#define BLK_BYTES 24576    // gi bytes per (t, 16-batch blk)
#define FLAGS_OFF 8781824  // 128 words (2 phases x 64)
#define GI_OFF 8785920     // 256*SLOT = 201,326,592 B; end 210,112,512
#define NPROD 224
#define NITEM 2048         // 64 tq x 32 blk per phase

__device__ __forceinline__ float b2f(ushort_t u) {
  return __uint_as_float(((unsigned)u) << 16);
}
__device__ __forceinline__ ushort_t f2b(float f) {
  unsigned u = __float_as_uint(f);
  return (ushort_t)((u + 0x7FFFu + ((u >> 16) & 1u)) >> 16);
}
__device__ __forceinline__ short8 ld8(const ushort_t* p) { return *(const short8*)p; }
__device__ __forceinline__ void gld_lds16(const void* g, void* l) {
  __builtin_amdgcn_global_load_lds((const __attribute__((address_space(1))) void*)g,
                                   (__attribute__((address_space(3))) void*)l, 16, 0, 0);
}
__device__ __forceinline__ int gi_byte(int bl, int c) {
  return ((bl * 1536) + c) ^ ((bl & 7) << 4);
}
// tid0 polls; barrier releases the block. No fence: data lines are first-touch
// within this launch and producer released (L2 wb) before setting the flag.
__device__ __forceinline__ void wait_item_block(const unsigned* flags, int item) {
  if (threadIdx.x == 0) {
    const unsigned bit = 1u << (item & 31);
    const unsigned* wp = flags + (item >> 5);
    while (!(__hip_atomic_load(wp, __ATOMIC_RELAXED, __HIP_MEMORY_SCOPE_AGENT) & bit))
      __builtin_amdgcn_s_sleep(2);
  }
  __builtin_amdgcn_s_barrier();
}

// ---------------- Phase A ----------------
__global__ void cvt_bf16_k(const float* __restrict__ s, ushort_t* __restrict__ d, int n4) {
  int i = blockIdx.x * blockDim.x + threadIdx.x;
  int stride = gridDim.x * blockDim.x;
  for (; i < n4; i += stride) {
    float4_ v = ((const float4_*)s)[i];
    ushort4_ o;
    o.x = f2b(v.x); o.y = f2b(v.y); o.z = f2b(v.z); o.w = f2b(v.w);
    ((ushort4_*)d)[i] = o;
  }
}

// ---------------- Phase B: fused producer/consumer, one 256-step phase ----------------
// LDS (consumer): ring[4][24576] @0 | h[2][8192] @98304              = 114688
// LDS (producer): img[4][24576] @0 | xe[64][256] @98304 | cb @114688 = 117760
__global__ __launch_bounds__(512, 1) void gru_fused(
    const int* __restrict__ x, const ushort_t* __restrict__ emb16,
    const ushort_t* __restrict__ Wih16, const ushort_t* __restrict__ Whh16,
    const float* __restrict__ bih, const float* __restrict__ bhh,
    char* __restrict__ gi, unsigned* __restrict__ flags,
    float* __restrict__ out, int phase) {
  __shared__ alignas(16) char smem[117760];
  const int tid = threadIdx.x, lane = tid & 63, w = tid >> 6;
  const int bl = lane & 15, kg = lane >> 4;
  const int s16 = (bl & 7) << 4;
  const unsigned* pflags = flags + phase * 64;

  if (blockIdx.x >= 32) {
    // ================= PRODUCER =================
    const int pid = blockIdx.x - 32;
    char* img = smem;
    char* xe = smem + 98304;
    float* cb = (float*)(smem + 114688);
    for (int i = tid; i < G3; i += 512) cb[i] = bih[i] + (i < 512 ? bhh[i] : 0.f);
    __syncthreads();

#pragma unroll 1
    for (int it = pid; it < NITEM; it += NPROD) {
      const int tq = it >> 5, blk = it & 31;
      const int t0 = tq * 4;                    // local slot base
      const int t0g = t0 + phase * CSTEPS;      // global timestep
      // stage xe: 64 rows (4t x 16b) of emb16, source-XOR, linear dest
#pragma unroll
      for (int gg = 0; gg < 2; ++gg) {
        int g = 2 * w + gg;
        int row = g * 4 + (lane >> 4);
        int tok = x[(blk * 16 + (row & 15)) * TT + t0g + (row >> 4)];
        const char* src = (const char*)emb16 + (size_t)((unsigned)tok) * 256u +
                          ((((unsigned)lane & 15u) << 4) ^ (((unsigned)row & 15u) << 4));
        gld_lds16(src, xe + g * 1024);
      }
      asm volatile("s_waitcnt vmcnt(0)" ::: "memory");
      __syncthreads();
      short8 bfr[4][4];
#pragma unroll
      for (int t = 0; t < 4; ++t)
#pragma unroll
        for (int kt = 0; kt < 4; ++kt)
          bfr[t][kt] = *(const short8*)(xe + (t * 16 + bl) * 256 +
                                        ((kt * 64 + kg * 16) ^ (bl << 4)));
#pragma unroll 1
      for (int mi = 0; mi < 6; ++mi) {
        int mt = w * 6 + mi;
        short8 af[4];
#pragma unroll
        for (int kt = 0; kt < 4; ++kt)
          af[kt] = ld8(Wih16 + (mt * 16 + bl) * EMB + kt * 32 + kg * 8);
        float4_ z4 = {0.f, 0.f, 0.f, 0.f};
        float4_ acc[4] = {z4, z4, z4, z4};
#pragma unroll
        for (int kt = 0; kt < 4; ++kt)
#pragma unroll
          for (int t = 0; t < 4; ++t)
            acc[t] = __builtin_amdgcn_mfma_f32_16x16x32_bf16(af[kt], bfr[t][kt], acc[t], 0, 0, 0);
        float4_ cbv = *(const float4_*)(cb + mt * 16 + kg * 4);
        int db = (bl * 1536 + 32 * mt + 8 * kg) ^ s16;
#pragma unroll
        for (int t = 0; t < 4; ++t) {
          ushort4_ o;
#pragma unroll
          for (int r = 0; r < 4; ++r) o[r] = f2b(acc[t][r] + cbv[r]);
          *(ushort4_*)(img + t * 24576 + db) = o;
        }
      }
      __syncthreads();
      // linear coalesced store (write-once region this launch)
      char* dstb = gi + (size_t)t0 * SLOT + (size_t)blk * BLK_BYTES;
#pragma unroll
      for (int t = 0; t < 4; ++t)
#pragma unroll
        for (int ii = 0; ii < 3; ++ii) {
          float4_ v = *(const float4_*)(img + t * 24576 + tid * 48 + ii * 16);
          *(float4_*)(dstb + (size_t)t * SLOT + tid * 48 + ii * 16) = v;
        }
      asm volatile("s_waitcnt vmcnt(0)" ::: "memory");
      __syncthreads();
      if (tid == 0)
        __hip_atomic_fetch_or((unsigned*)&pflags[it >> 5], 1u << (it & 31),
                              __ATOMIC_RELEASE, __HIP_MEMORY_SCOPE_AGENT);
    }
    return;
  }

  // ================= CONSUMER (R7-proven body, 256 steps) =================
  const int bx = blockIdx.x;
  const int b0 = bx * 16;

  if (phase == 0) {
    int4_ z4 = {0, 0, 0, 0};
    *(int4_*)(smem + 98304 + tid * 16) = z4;  // zero h[0]
  } else {
    for (int i = tid; i < 16 * HID; i += 512) {
      int b = i >> 8, k = i & 255;
      *(ushort_t*)(smem + 98304 + (((b << 9) + 2 * k) ^ ((b & 7) << 4))) =
          f2b(out[(size_t)(b0 + b) * HID + k]);
    }
  }
  __syncthreads();

  short8 wf[2][3][8];
#pragma unroll
  for (int i = 0; i < 2; ++i)
#pragma unroll
    for (int q = 0; q < 3; ++q) {
      int g = (w + 8 * i + 16 * q) * 16 + bl;
#pragma unroll
      for (int kt = 0; kt < 8; ++kt)
        wf[i][q][kt] = ld8(Whh16 + (size_t)g * HID + kt * 32 + kg * 8);
    }

  float4_ bhn[2];
  float hreg[2][4];
#pragma unroll
  for (int i = 0; i < 2; ++i) {
    bhn[i] = *(const float4_*)&bhh[512 + (w + 8 * i) * 16 + kg * 4];
    if (phase == 0) {
#pragma unroll
      for (int r = 0; r < 4; ++r) hreg[i][r] = 0.f;
    } else {
      float4_ v = *(const float4_*)&out[(size_t)(b0 + bl) * HID + (w + 8 * i) * 16 + kg * 4];
#pragma unroll
      for (int r = 0; r < 4; ++r) hreg[i][r] = v[r];
    }
  }

  asm volatile("s_waitcnt vmcnt(0) lgkmcnt(0)" ::: "memory");
  __builtin_amdgcn_s_barrier();
  __builtin_amdgcn_sched_barrier(0);

  // prologue: item (tq=0, bx) covers t=0..3 -> stage slots 0..2
  wait_item_block(pflags, bx);
#pragma unroll
  for (int tau = 0; tau < 3; ++tau) {
    const char* src = gi + (size_t)tau * SLOT + (size_t)bx * BLK_BYTES + (w * 3) * 1024 + lane * 16;
    char* dst = smem + tau * 24576 + (w * 3) * 1024;
#pragma unroll
    for (int ii = 0; ii < 3; ++ii) gld_lds16(src + ii * 1024, dst + ii * 1024);
  }

#pragma unroll 1
  for (int t = 0; t < CSTEPS; ++t) {
    int rem = CSTEPS - 1 - t;
    if (rem >= 2)
      asm volatile("s_waitcnt vmcnt(6) lgkmcnt(0)" ::: "memory");
    else if (rem == 1)
      asm volatile("s_waitcnt vmcnt(3) lgkmcnt(0)" ::: "memory");
    else
      asm volatile("s_waitcnt vmcnt(0) lgkmcnt(0)" ::: "memory");
    __builtin_amdgcn_s_barrier();
    __builtin_amdgcn_sched_barrier(0);

    const int slot = t & 3, cur = t & 1, nxt = cur ^ 1;
    if (t + 3 < CSTEPS) {
      if (((t + 3) & 3) == 0) wait_item_block(pflags, ((t + 3) >> 2) * 32 + bx);
      const char* src = gi + (size_t)(t + 3) * SLOT +
                        (size_t)bx * BLK_BYTES + (w * 3) * 1024 + lane * 16;
      char* dst = smem + ((t + 3) & 3) * 24576 + (w * 3) * 1024;
#pragma unroll
      for (int ii = 0; ii < 3; ++ii) gld_lds16(src + ii * 1024, dst + ii * 1024);
    }

    const char* gtile = smem + slot * 24576;

    float4_ acc[2][3];
#pragma unroll
    for (int i = 0; i < 2; ++i) {
#pragma unroll
      for (int q = 0; q < 2; ++q) {
        int byte8 = gi_byte(bl, 32 * (w + 8 * i + 16 * q) + 8 * kg);
        ushort4_ v = *(const ushort4_*)(gtile + byte8);
#pragma unroll
        for (int r = 0; r < 4; ++r) acc[i][q][r] = b2f(v[r]);
      }
      acc[i][2] = bhn[i];
    }

#pragma unroll
    for (int kt = 0; kt < 8; ++kt) {
      int byteoff = ((bl * 512) + kt * 64 + kg * 16) ^ s16;
      short8 bf = *(const short8*)(smem + 98304 + cur * 8192 + byteoff);
#pragma unroll
      for (int i = 0; i < 2; ++i)
#pragma unroll
        for (int q = 0; q < 3; ++q)
          acc[i][q] = __builtin_amdgcn_mfma_f32_16x16x32_bf16(wf[i][q][kt], bf, acc[i][q], 0, 0, 0);
    }

#pragma unroll
    for (int i = 0; i < 2; ++i) {
      int byte8n = gi_byte(bl, 32 * (32 + w + 8 * i) + 8 * kg);
      ushort4_ gv = *(const ushort4_*)(gtile + byte8n);
#pragma unroll
      for (int r = 0; r < 4; ++r) {
        float rr = __builtin_amdgcn_rcpf(1.f + __expf(-acc[i][0][r]));
        float zz = __builtin_amdgcn_rcpf(1.f + __expf(-acc[i][1][r]));
        float y = b2f(gv[r]) + rr * acc[i][2][r];
        float nn = 1.f - 2.f * __builtin_amdgcn_rcpf(1.f + __expf(2.f * y));
        hreg[i][r] = (1.f - zz) * nn + zz * hreg[i][r];
      }
      int byte0 = (bl * 512 + ((w + 8 * i) * 16 + kg * 4) * 2) ^ s16;
      uint2_ hv;
      hv.x = (unsigned)f2b(hreg[i][0]) | ((unsigned)f2b(hreg[i][1]) << 16);
      hv.y = (unsigned)f2b(hreg[i][2]) | ((unsigned)f2b(hreg[i][3]) << 16);
      *(uint2_*)(smem + 98304 + nxt * 8192 + byte0) = hv;
    }
  }

#pragma unroll
  for (int i = 0; i < 2; ++i) {
    float4_ v = {hreg[i][0], hreg[i][1], hreg[i][2], hreg[i][3]};
    *(float4_*)&out[(size_t)(b0 + bl) * HID + (w + 8 * i) * 16 + kg * 4] = v;
  }
}

extern "C" void kernel_launch(void* const* d_in, const int* in_sizes, int n_in,
                              void* d_out, int out_size, void* d_ws, size_t ws_size,
                              hipStream_t stream) {
  const int* x = (const int*)d_in[0];
  const float* emb = (const float*)d_in[1];
  const float* Wih = (const float*)d_in[2];
  const float* Whh = (const float*)d_in[3];
  const float* bih = (const float*)d_in[4];
  const float* bhh = (const float*)d_in[5];
  float* out = (float*)d_out;

  char* ws = (char*)d_ws;
  ushort_t* emb16 = (ushort_t*)ws;                 // 8,192,000 B
  ushort_t* Wih16 = (ushort_t*)(ws + 8192000);     //   196,608 B
  ushort_t* Whh16 = (ushort_t*)(ws + 8388608);     //   393,216 B
  unsigned* flags = (unsigned*)(ws + FLAGS_OFF);   //       512 B (2 phases x 64 words)
  char* gi = ws + GI_OFF;                          // 201,326,592 B, write-once/launch

  cvt_bf16_k<<<1024, 256, 0, stream>>>(emb, emb16, (VOCAB * EMB) / 4);
  cvt_bf16_k<<<96, 256, 0, stream>>>(Wih, Wih16, (G3 * EMB) / 4);
  cvt_bf16_k<<<192, 256, 0, stream>>>(Whh, Whh16, (G3 * HID) / 4);
  hipMemsetAsync(ws + FLAGS_OFF, 0, 512, stream);
  gru_fused<<<256, 512, 0, stream>>>(x, emb16, Wih16, Whh16, bih, bhh, gi, flags, out, 0);
  gru_fused<<<256, 512, 0, stream>>>(x, emb16, Wih16, Whh16, bih, bhh, gi, flags, out, 1);
}

// Round 11
// 1426.780 us; speedup vs baseline: 1.1889x; 1.0574x over previous
//
#include <hip/hip_runtime.h>

// GRU, producer-consumer fused, TWO launches of 256 steps (write-once gi per launch).
// R11 change vs R10: producer gi stores are coherence-point write-through
// (global_store_dwordx4 sc0 sc1), so the per-item flag release needs NO agent fence
// (no per-item L2 writeback). Flag set is a relaxed fetch_or after vmcnt(0).
//   blocks 0-31   consumers: R7-proven recurrence, 256 steps, 4-deep LDS ring,
//                 counted vmcnt, 1 barrier/step; tid0 flag poll per item (4 steps).
//   blocks 32-255 producers: 2048 items (4t x 16-batch tile) via MFMA.
//   h crosses the launch boundary via d_out (f32, exact).

typedef unsigned short ushort_t;
typedef __attribute__((ext_vector_type(8))) short short8;
typedef __attribute__((ext_vector_type(4))) float float4_;
typedef __attribute__((ext_vector_type(4))) unsigned short ushort4_;
typedef __attribute__((ext_vector_type(2))) unsigned int uint2_;
typedef __attribute__((ext_vector_type(4))) int int4_;

#define VOCAB 32000
#define EMB 128
#define HID 256
#define G3 768
#define TT 512
#define CSTEPS 256         // steps per launch
#define SLOT 786432        // gi bytes per timestep
#define BLK_BYTES 24576    // gi bytes per (t, 16-batch blk)
#define FLAGS_OFF 8781824  // 128 words (2 phases x 64)
#define GI_OFF 8785920     // 256*SLOT = 201,326,592 B
#define NPROD 224
#define NITEM 2048         // 64 tq x 32 blk per phase

__device__ __forceinline__ float b2f(ushort_t u) {
  return __uint_as_float(((unsigned)u) << 16);
}
__device__ __forceinline__ ushort_t f2b(float f) {
  unsigned u = __float_as_uint(f);
  return (ushort_t)((u + 0x7FFFu + ((u >> 16) & 1u)) >> 16);
}
__device__ __forceinline__ short8 ld8(const ushort_t* p) { return *(const short8*)p; }
__device__ __forceinline__ void gld_lds16(const void* g, void* l) {
  __builtin_amdgcn_global_load_lds((const __attribute__((address_space(1))) void*)g,
                                   (__attribute__((address_space(3))) void*)l, 16, 0, 0);
}
__device__ __forceinline__ int gi_byte(int bl, int c) {
  return ((bl * 1536) + c) ^ ((bl & 7) << 4);
}
// write-through store: ack at coherence point, leaves no dirty L2 line
__device__ __forceinline__ void store16_wt(void* p, float4_ v) {
  asm volatile("global_store_dwordx4 %0, %1, off sc0 sc1" ::"v"(p), "v"(v) : "memory");
}
// tid0 polls; barrier releases the block. No fence (write-once + dispatch acquire).
__device__ __forceinline__ void wait_item_block(const unsigned* flags, int item) {
  if (threadIdx.x == 0) {
    const unsigned bit = 1u << (item & 31);
    const unsigned* wp = flags + (item >> 5);
    while (!(__hip_atomic_load(wp, __ATOMIC_RELAXED, __HIP_MEMORY_SCOPE_AGENT) & bit))
      __builtin_amdgcn_s_sleep(2);
  }
  __builtin_amdgcn_s_barrier();
}

// ---------------- Phase A ----------------
__global__ void cvt_bf16_k(const float* __restrict__ s, ushort_t* __restrict__ d, int n4) {
  int i = blockIdx.x * blockDim.x + threadIdx.x;
  int stride = gridDim.x * blockDim.x;
  for (; i < n4; i += stride) {
    float4_ v = ((const float4_*)s)[i];
    ushort4_ o;
    o.x = f2b(v.x); o.y = f2b(v.y); o.z = f2b(v.z); o.w = f2b(v.w);
    ((ushort4_*)d)[i] = o;
  }
}

// ---------------- Phase B: fused producer/consumer, one 256-step phase ----------------
// LDS (consumer): ring[4][24576] @0 | h[2][8192] @98304              = 114688
// LDS (producer): img[4][24576] @0 | xe[64][256] @98304 | cb @114688 = 117760
__global__ __launch_bounds__(512, 1) void gru_fused(
    const int* __restrict__ x, const ushort_t* __restrict__ emb16,
    const ushort_t* __restrict__ Wih16, const ushort_t* __restrict__ Whh16,
    const float* __restrict__ bih, const float* __restrict__ bhh,
    char* __restrict__ gi, unsigned* __restrict__ flags,
    float* __restrict__ out, int phase) {
  __shared__ alignas(16) char smem[117760];
  const int tid = threadIdx.x, lane = tid & 63, w = tid >> 6;
  const int bl = lane & 15, kg = lane >> 4;
  const int s16 = (bl & 7) << 4;
  const unsigned* pflags = flags + phase * 64;

  if (blockIdx.x >= 32) {
    // ================= PRODUCER =================
    const int pid = blockIdx.x - 32;
    char* img = smem;
    char* xe = smem + 98304;
    float* cb = (float*)(smem + 114688);
    for (int i = tid; i < G3; i += 512) cb[i] = bih[i] + (i < 512 ? bhh[i] : 0.f);
    __syncthreads();

#pragma unroll 1
    for (int it = pid; it < NITEM; it += NPROD) {
      const int tq = it >> 5, blk = it & 31;
      const int t0 = tq * 4;                    // local slot base
      const int t0g = t0 + phase * CSTEPS;      // global timestep
      // stage xe: 64 rows (4t x 16b) of emb16, source-XOR, linear dest
#pragma unroll
      for (int gg = 0; gg < 2; ++gg) {
        int g = 2 * w + gg;
        int row = g * 4 + (lane >> 4);
        int tok = x[(blk * 16 + (row & 15)) * TT + t0g + (row >> 4)];
        const char* src = (const char*)emb16 + (size_t)((unsigned)tok) * 256u +
                          ((((unsigned)lane & 15u) << 4) ^ (((unsigned)row & 15u) << 4));
        gld_lds16(src, xe + g * 1024);
      }
      asm volatile("s_waitcnt vmcnt(0)" ::: "memory");
      __syncthreads();
      short8 bfr[4][4];
#pragma unroll
      for (int t = 0; t < 4; ++t)
#pragma unroll
        for (int kt = 0; kt < 4; ++kt)
          bfr[t][kt] = *(const short8*)(xe + (t * 16 + bl) * 256 +
                                        ((kt * 64 + kg * 16) ^ (bl << 4)));
#pragma unroll 1
      for (int mi = 0; mi < 6; ++mi) {
        int mt = w * 6 + mi;
        short8 af[4];
#pragma unroll
        for (int kt = 0; kt < 4; ++kt)
          af[kt] = ld8(Wih16 + (mt * 16 + bl) * EMB + kt * 32 + kg * 8);
        float4_ z4 = {0.f, 0.f, 0.f, 0.f};
        float4_ acc[4] = {z4, z4, z4, z4};
#pragma unroll
        for (int kt = 0; kt < 4; ++kt)
#pragma unroll
          for (int t = 0; t < 4; ++t)
            acc[t] = __builtin_amdgcn_mfma_f32_16x16x32_bf16(af[kt], bfr[t][kt], acc[t], 0, 0, 0);
        float4_ cbv = *(const float4_*)(cb + mt * 16 + kg * 4);
        int db = (bl * 1536 + 32 * mt + 8 * kg) ^ s16;
#pragma unroll
        for (int t = 0; t < 4; ++t) {
          ushort4_ o;
#pragma unroll
          for (int r = 0; r < 4; ++r) o[r] = f2b(acc[t][r] + cbv[r]);
          *(ushort4_*)(img + t * 24576 + db) = o;
        }
      }
      __syncthreads();
      // write-through coalesced store (no dirty L2 -> no wbL2 needed at release)
      char* dstb = gi + (size_t)t0 * SLOT + (size_t)blk * BLK_BYTES;
#pragma unroll
      for (int t = 0; t < 4; ++t)
#pragma unroll
        for (int ii = 0; ii < 3; ++ii) {
          float4_ v = *(const float4_*)(img + t * 24576 + tid * 48 + ii * 16);
          store16_wt(dstb + (size_t)t * SLOT + tid * 48 + ii * 16, v);
        }
      asm volatile("s_waitcnt vmcnt(0)" ::: "memory");
      __syncthreads();
      if (tid == 0)
        __hip_atomic_fetch_or((unsigned*)&pflags[it >> 5], 1u << (it & 31),
                              __ATOMIC_RELAXED, __HIP_MEMORY_SCOPE_AGENT);
    }
    return;
  }

  // ================= CONSUMER (R7-proven body, 256 steps) =================
  const int bx = blockIdx.x;
  const int b0 = bx * 16;

  if (phase == 0) {
    int4_ z4 = {0, 0, 0, 0};
    *(int4_*)(smem + 98304 + tid * 16) = z4;  // zero h[0]
  } else {
    for (int i = tid; i < 16 * HID; i += 512) {
      int b = i >> 8, k = i & 255;
      *(ushort_t*)(smem + 98304 + (((b << 9) + 2 * k) ^ ((b & 7) << 4))) =
          f2b(out[(size_t)(b0 + b) * HID + k]);
    }
  }
  __syncthreads();

  short8 wf[2][3][8];
#pragma unroll
  for (int i = 0; i < 2; ++i)
#pragma unroll
    for (int q = 0; q < 3; ++q) {
      int g = (w + 8 * i + 16 * q) * 16 + bl;
#pragma unroll
      for (int kt = 0; kt < 8; ++kt)
        wf[i][q][kt] = ld8(Whh16 + (size_t)g * HID + kt * 32 + kg * 8);
    }

  float4_ bhn[2];
  float hreg[2][4];
#pragma unroll
  for (int i = 0; i < 2; ++i) {
    bhn[i] = *(const float4_*)&bhh[512 + (w + 8 * i) * 16 + kg * 4];
    if (phase == 0) {
#pragma unroll
      for (int r = 0; r < 4; ++r) hreg[i][r] = 0.f;
    } else {
      float4_ v = *(const float4_*)&out[(size_t)(b0 + bl) * HID + (w + 8 * i) * 16 + kg * 4];
#pragma unroll
      for (int r = 0; r < 4; ++r) hreg[i][r] = v[r];
    }
  }

  asm volatile("s_waitcnt vmcnt(0) lgkmcnt(0)" ::: "memory");
  __builtin_amdgcn_s_barrier();
  __builtin_amdgcn_sched_barrier(0);

  // prologue: item (tq=0, bx) covers t=0..3 -> stage slots 0..2
  wait_item_block(pflags, bx);
#pragma unroll
  for (int tau = 0; tau < 3; ++tau) {
    const char* src = gi + (size_t)tau * SLOT + (size_t)bx * BLK_BYTES + (w * 3) * 1024 + lane * 16;
    char* dst = smem + tau * 24576 + (w * 3) * 1024;
#pragma unroll
    for (int ii = 0; ii < 3; ++ii) gld_lds16(src + ii * 1024, dst + ii * 1024);
  }

#pragma unroll 1
  for (int t = 0; t < CSTEPS; ++t) {
    int rem = CSTEPS - 1 - t;
    if (rem >= 2)
      asm volatile("s_waitcnt vmcnt(6) lgkmcnt(0)" ::: "memory");
    else if (rem == 1)
      asm volatile("s_waitcnt vmcnt(3) lgkmcnt(0)" ::: "memory");
    else
      asm volatile("s_waitcnt vmcnt(0) lgkmcnt(0)" ::: "memory");
    __builtin_amdgcn_s_barrier();
    __builtin_amdgcn_sched_barrier(0);

    const int slot = t & 3, cur = t & 1, nxt = cur ^ 1;
    if (t + 3 < CSTEPS) {
      if (((t + 3) & 3) == 0) wait_item_block(pflags, ((t + 3) >> 2) * 32 + bx);
      const char* src = gi + (size_t)(t + 3) * SLOT +
                        (size_t)bx * BLK_BYTES + (w * 3) * 1024 + lane * 16;
      char* dst = smem + ((t + 3) & 3) * 24576 + (w * 3) * 1024;
#pragma unroll
      for (int ii = 0; ii < 3; ++ii) gld_lds16(src + ii * 1024, dst + ii * 1024);
    }

    const char* gtile = smem + slot * 24576;

    float4_ acc[2][3];
#pragma unroll
    for (int i = 0; i < 2; ++i) {
#pragma unroll
      for (int q = 0; q < 2; ++q) {
        int byte8 = gi_byte(bl, 32 * (w + 8 * i + 16 * q) + 8 * kg);
        ushort4_ v = *(const ushort4_*)(gtile + byte8);
#pragma unroll
        for (int r = 0; r < 4; ++r) acc[i][q][r] = b2f(v[r]);
      }
      acc[i][2] = bhn[i];
    }

#pragma unroll
    for (int kt = 0; kt < 8; ++kt) {
      int byteoff = ((bl * 512) + kt * 64 + kg * 16) ^ s16;
      short8 bf = *(const short8*)(smem + 98304 + cur * 8192 + byteoff);
#pragma unroll
      for (int i = 0; i < 2; ++i)
#pragma unroll
        for (int q = 0; q < 3; ++q)
          acc[i][q] = __builtin_amdgcn_mfma_f32_16x16x32_bf16(wf[i][q][kt], bf, acc[i][q], 0, 0, 0);
    }

#pragma unroll
    for (int i = 0; i < 2; ++i) {
      int byte8n = gi_byte(bl, 32 * (32 + w + 8 * i) + 8 * kg);
      ushort4_ gv = *(const ushort4_*)(gtile + byte8n);
#pragma unroll
      for (int r = 0; r < 4; ++r) {
        float rr = __builtin_amdgcn_rcpf(1.f + __expf(-acc[i][0][r]));
        float zz = __builtin_amdgcn_rcpf(1.f + __expf(-acc[i][1][r]));
        float y = b2f(gv[r]) + rr * acc[i][2][r];
        float nn = 1.f - 2.f * __builtin_amdgcn_rcpf(1.f + __expf(2.f * y));
        hreg[i][r] = (1.f - zz) * nn + zz * hreg[i][r];
      }
      int byte0 = (bl * 512 + ((w + 8 * i) * 16 + kg * 4) * 2) ^ s16;
      uint2_ hv;
      hv.x = (unsigned)f2b(hreg[i][0]) | ((unsigned)f2b(hreg[i][1]) << 16);
      hv.y = (unsigned)f2b(hreg[i][2]) | ((unsigned)f2b(hreg[i][3]) << 16);
      *(uint2_*)(smem + 98304 + nxt * 8192 + byte0) = hv;
    }
  }

#pragma unroll
  for (int i = 0; i < 2; ++i) {
    float4_ v = {hreg[i][0], hreg[i][1], hreg[i][2], hreg[i][3]};
    *(float4_*)&out[(size_t)(b0 + bl) * HID + (w + 8 * i) * 16 + kg * 4] = v;
  }
}

extern "C" void kernel_launch(void* const* d_in, const int* in_sizes, int n_in,
                              void* d_out, int out_size, void* d_ws, size_t ws_size,
                              hipStream_t stream) {
  const int* x = (const int*)d_in[0];
  const float* emb = (const float*)d_in[1];
  const float* Wih = (const float*)d_in[2];
  const float* Whh = (const float*)d_in[3];
  const float* bih = (const float*)d_in[4];
  const float* bhh = (const float*)d_in[5];
  float* out = (float*)d_out;

  char* ws = (char*)d_ws;
  ushort_t* emb16 = (ushort_t*)ws;                 // 8,192,000 B
  ushort_t* Wih16 = (ushort_t*)(ws + 8192000);     //   196,608 B
  ushort_t* Whh16 = (ushort_t*)(ws + 8388608);     //   393,216 B
  unsigned* flags = (unsigned*)(ws + FLAGS_OFF);   //       512 B (2 phases x 64 words)
  char* gi = ws + GI_OFF;                          // 201,326,592 B, write-once/launch

  cvt_bf16_k<<<1024, 256, 0, stream>>>(emb, emb16, (VOCAB * EMB) / 4);
  cvt_bf16_k<<<96, 256, 0, stream>>>(Wih, Wih16, (G3 * EMB) / 4);
  cvt_bf16_k<<<192, 256, 0, stream>>>(Whh, Whh16, (G3 * HID) / 4);
  hipMemsetAsync(ws + FLAGS_OFF, 0, 512, stream);
  gru_fused<<<256, 512, 0, stream>>>(x, emb16, Wih16, Whh16, bih, bhh, gi, flags, out, 0);
  gru_fused<<<256, 512, 0, stream>>>(x, emb16, Wih16, Whh16, bih, bhh, gi, flags, out, 1);
}

// Round 12
// 1331.511 us; speedup vs baseline: 1.2739x; 1.0715x over previous
//
#include <hip/hip_runtime.h>

// GRU, producer-consumer fused, TWO launches of 256 steps (write-once gi per launch).
// R12 change vs R11: XCD role segregation. Round-robin dispatch maps block b to
// XCD b%8, so consumers = blocks with b%8==0 (all on XCD0, whose L2 then serves
// ONLY consumer traffic); producers = remaining 224 blocks (XCDs 1-7).
// Producer stores stay coherence-point write-through (sc0 sc1) + relaxed flags
// (R11-proven, no per-item wbL2).
//   h crosses the launch boundary via d_out (f32, exact).

typedef unsigned short ushort_t;
typedef __attribute__((ext_vector_type(8))) short short8;
typedef __attribute__((ext_vector_type(4))) float float4_;
typedef __attribute__((ext_vector_type(4))) unsigned short ushort4_;
typedef __attribute__((ext_vector_type(2))) unsigned int uint2_;
typedef __attribute__((ext_vector_type(4))) int int4_;

#define VOCAB 32000
#define EMB 128
#define HID 256
#define G3 768
#define TT 512
#define CSTEPS 256         // steps per launch
#define SLOT 786432        // gi bytes per timestep
#define BLK_BYTES 24576    // gi bytes per (t, 16-batch blk)
#define FLAGS_OFF 8781824  // 128 words (2 phases x 64)
#define GI_OFF 8785920     // 256*SLOT = 201,326,592 B
#define NPROD 224
#define NITEM 2048         // 64 tq x 32 blk per phase

__device__ __forceinline__ float b2f(ushort_t u) {
  return __uint_as_float(((unsigned)u) << 16);
}
__device__ __forceinline__ ushort_t f2b(float f) {
  unsigned u = __float_as_uint(f);
  return (ushort_t)((u + 0x7FFFu + ((u >> 16) & 1u)) >> 16);
}
__device__ __forceinline__ short8 ld8(const ushort_t* p) { return *(const short8*)p; }
__device__ __forceinline__ void gld_lds16(const void* g, void* l) {
  __builtin_amdgcn_global_load_lds((const __attribute__((address_space(1))) void*)g,
                                   (__attribute__((address_space(3))) void*)l, 16, 0, 0);
}
__device__ __forceinline__ int gi_byte(int bl, int c) {
  return ((bl * 1536) + c) ^ ((bl & 7) << 4);
}
// write-through store: ack at coherence point, leaves no dirty L2 line
__device__ __forceinline__ void store16_wt(void* p, float4_ v) {
  asm volatile("global_store_dwordx4 %0, %1, off sc0 sc1" ::"v"(p), "v"(v) : "memory");
}
// tid0 polls; barrier releases the block. No fence (write-once + dispatch acquire).
__device__ __forceinline__ void wait_item_block(const unsigned* flags, int item) {
  if (threadIdx.x == 0) {
    const unsigned bit = 1u << (item & 31);
    const unsigned* wp = flags + (item >> 5);
    while (!(__hip_atomic_load(wp, __ATOMIC_RELAXED, __HIP_MEMORY_SCOPE_AGENT) & bit))
      __builtin_amdgcn_s_sleep(2);
  }
  __builtin_amdgcn_s_barrier();
}

// ---------------- Phase A ----------------
__global__ void cvt_bf16_k(const float* __restrict__ s, ushort_t* __restrict__ d, int n4) {
  int i = blockIdx.x * blockDim.x + threadIdx.x;
  int stride = gridDim.x * blockDim.x;
  for (; i < n4; i += stride) {
    float4_ v = ((const float4_*)s)[i];
    ushort4_ o;
    o.x = f2b(v.x); o.y = f2b(v.y); o.z = f2b(v.z); o.w = f2b(v.w);
    ((ushort4_*)d)[i] = o;
  }
}

// ---------------- Phase B: fused producer/consumer, one 256-step phase ----------------
// LDS (consumer): ring[4][24576] @0 | h[2][8192] @98304              = 114688
// LDS (producer): img[4][24576] @0 | xe[64][256] @98304 | cb @114688 = 117760
__global__ __launch_bounds__(512, 1) void gru_fused(
    const int* __restrict__ x, const ushort_t* __restrict__ emb16,
    const ushort_t* __restrict__ Wih16, const ushort_t* __restrict__ Whh16,
    const float* __restrict__ bih, const float* __restrict__ bhh,
    char* __restrict__ gi, unsigned* __restrict__ flags,
    float* __restrict__ out, int phase) {
  __shared__ alignas(16) char smem[117760];
  const int tid = threadIdx.x, lane = tid & 63, w = tid >> 6;
  const int bl = lane & 15, kg = lane >> 4;
  const int s16 = (bl & 7) << 4;
  const unsigned* pflags = flags + phase * 64;

  if ((blockIdx.x & 7) != 0) {
    // ================= PRODUCER (XCDs 1-7 under round-robin) =================
    const int pid = blockIdx.x - 1 - (blockIdx.x >> 3);  // 0..223, bijective
    char* img = smem;
    char* xe = smem + 98304;
    float* cb = (float*)(smem + 114688);
    for (int i = tid; i < G3; i += 512) cb[i] = bih[i] + (i < 512 ? bhh[i] : 0.f);
    __syncthreads();

#pragma unroll 1
    for (int it = pid; it < NITEM; it += NPROD) {
      const int tq = it >> 5, blk = it & 31;
      const int t0 = tq * 4;                    // local slot base
      const int t0g = t0 + phase * CSTEPS;      // global timestep
      // stage xe: 64 rows (4t x 16b) of emb16, source-XOR, linear dest
#pragma unroll
      for (int gg = 0; gg < 2; ++gg) {
        int g = 2 * w + gg;
        int row = g * 4 + (lane >> 4);
        int tok = x[(blk * 16 + (row & 15)) * TT + t0g + (row >> 4)];
        const char* src = (const char*)emb16 + (size_t)((unsigned)tok) * 256u +
                          ((((unsigned)lane & 15u) << 4) ^ (((unsigned)row & 15u) << 4));
        gld_lds16(src, xe + g * 1024);
      }
      asm volatile("s_waitcnt vmcnt(0)" ::: "memory");
      __syncthreads();
      short8 bfr[4][4];
#pragma unroll
      for (int t = 0; t < 4; ++t)
#pragma unroll
        for (int kt = 0; kt < 4; ++kt)
          bfr[t][kt] = *(const short8*)(xe + (t * 16 + bl) * 256 +
                                        ((kt * 64 + kg * 16) ^ (bl << 4)));
#pragma unroll 1
      for (int mi = 0; mi < 6; ++mi) {
        int mt = w * 6 + mi;
        short8 af[4];
#pragma unroll
        for (int kt = 0; kt < 4; ++kt)
          af[kt] = ld8(Wih16 + (mt * 16 + bl) * EMB + kt * 32 + kg * 8);
        float4_ z4 = {0.f, 0.f, 0.f, 0.f};
        float4_ acc[4] = {z4, z4, z4, z4};
#pragma unroll
        for (int kt = 0; kt < 4; ++kt)
#pragma unroll
          for (int t = 0; t < 4; ++t)
            acc[t] = __builtin_amdgcn_mfma_f32_16x16x32_bf16(af[kt], bfr[t][kt], acc[t], 0, 0, 0);
        float4_ cbv = *(const float4_*)(cb + mt * 16 + kg * 4);
        int db = (bl * 1536 + 32 * mt + 8 * kg) ^ s16;
#pragma unroll
        for (int t = 0; t < 4; ++t) {
          ushort4_ o;
#pragma unroll
          for (int r = 0; r < 4; ++r) o[r] = f2b(acc[t][r] + cbv[r]);
          *(ushort4_*)(img + t * 24576 + db) = o;
        }
      }
      __syncthreads();
      // write-through coalesced store (no dirty L2 -> no wbL2 needed at release)
      char* dstb = gi + (size_t)t0 * SLOT + (size_t)blk * BLK_BYTES;
#pragma unroll
      for (int t = 0; t < 4; ++t)
#pragma unroll
        for (int ii = 0; ii < 3; ++ii) {
          float4_ v = *(const float4_*)(img + t * 24576 + tid * 48 + ii * 16);
          store16_wt(dstb + (size_t)t * SLOT + tid * 48 + ii * 16, v);
        }
      asm volatile("s_waitcnt vmcnt(0)" ::: "memory");
      __syncthreads();
      if (tid == 0)
        __hip_atomic_fetch_or((unsigned*)&pflags[it >> 5], 1u << (it & 31),
                              __ATOMIC_RELAXED, __HIP_MEMORY_SCOPE_AGENT);
    }
    return;
  }

  // ================= CONSUMER (XCD0 under round-robin; R7-proven body) ============
  const int bx = blockIdx.x >> 3;  // 0..31
  const int b0 = bx * 16;

  if (phase == 0) {
    int4_ z4 = {0, 0, 0, 0};
    *(int4_*)(smem + 98304 + tid * 16) = z4;  // zero h[0]
  } else {
    for (int i = tid; i < 16 * HID; i += 512) {
      int b = i >> 8, k = i & 255;
      *(ushort_t*)(smem + 98304 + (((b << 9) + 2 * k) ^ ((b & 7) << 4))) =
          f2b(out[(size_t)(b0 + b) * HID + k]);
    }
  }
  __syncthreads();

  short8 wf[2][3][8];
#pragma unroll
  for (int i = 0; i < 2; ++i)
#pragma unroll
    for (int q = 0; q < 3; ++q) {
      int g = (w + 8 * i + 16 * q) * 16 + bl;
#pragma unroll
      for (int kt = 0; kt < 8; ++kt)
        wf[i][q][kt] = ld8(Whh16 + (size_t)g * HID + kt * 32 + kg * 8);
    }

  float4_ bhn[2];
  float hreg[2][4];
#pragma unroll
  for (int i = 0; i < 2; ++i) {
    bhn[i] = *(const float4_*)&bhh[512 + (w + 8 * i) * 16 + kg * 4];
    if (phase == 0) {
#pragma unroll
      for (int r = 0; r < 4; ++r) hreg[i][r] = 0.f;
    } else {
      float4_ v = *(const float4_*)&out[(size_t)(b0 + bl) * HID + (w + 8 * i) * 16 + kg * 4];
#pragma unroll
      for (int r = 0; r < 4; ++r) hreg[i][r] = v[r];
    }
  }

  asm volatile("s_waitcnt vmcnt(0) lgkmcnt(0)" ::: "memory");
  __builtin_amdgcn_s_barrier();
  __builtin_amdgcn_sched_barrier(0);

  // prologue: item (tq=0, bx) covers t=0..3 -> stage slots 0..2
  wait_item_block(pflags, bx);
#pragma unroll
  for (int tau = 0; tau < 3; ++tau) {
    const char* src = gi + (size_t)tau * SLOT + (size_t)bx * BLK_BYTES + (w * 3) * 1024 + lane * 16;
    char* dst = smem + tau * 24576 + (w * 3) * 1024;
#pragma unroll
    for (int ii = 0; ii < 3; ++ii) gld_lds16(src + ii * 1024, dst + ii * 1024);
  }

#pragma unroll 1
  for (int t = 0; t < CSTEPS; ++t) {
    int rem = CSTEPS - 1 - t;
    if (rem >= 2)
      asm volatile("s_waitcnt vmcnt(6) lgkmcnt(0)" ::: "memory");
    else if (rem == 1)
      asm volatile("s_waitcnt vmcnt(3) lgkmcnt(0)" ::: "memory");
    else
      asm volatile("s_waitcnt vmcnt(0) lgkmcnt(0)" ::: "memory");
    __builtin_amdgcn_s_barrier();
    __builtin_amdgcn_sched_barrier(0);

    const int slot = t & 3, cur = t & 1, nxt = cur ^ 1;
    if (t + 3 < CSTEPS) {
      if (((t + 3) & 3) == 0) wait_item_block(pflags, ((t + 3) >> 2) * 32 + bx);
      const char* src = gi + (size_t)(t + 3) * SLOT +
                        (size_t)bx * BLK_BYTES + (w * 3) * 1024 + lane * 16;
      char* dst = smem + ((t + 3) & 3) * 24576 + (w * 3) * 1024;
#pragma unroll
      for (int ii = 0; ii < 3; ++ii) gld_lds16(src + ii * 1024, dst + ii * 1024);
    }

    const char* gtile = smem + slot * 24576;

    float4_ acc[2][3];
#pragma unroll
    for (int i = 0; i < 2; ++i) {
#pragma unroll
      for (int q = 0; q < 2; ++q) {
        int byte8 = gi_byte(bl, 32 * (w + 8 * i + 16 * q) + 8 * kg);
        ushort4_ v = *(const ushort4_*)(gtile + byte8);
#pragma unroll
        for (int r = 0; r < 4; ++r) acc[i][q][r] = b2f(v[r]);
      }
      acc[i][2] = bhn[i];
    }

#pragma unroll
    for (int kt = 0; kt < 8; ++kt) {
      int byteoff = ((bl * 512) + kt * 64 + kg * 16) ^ s16;
      short8 bf = *(const short8*)(smem + 98304 + cur * 8192 + byteoff);
#pragma unroll
      for (int i = 0; i < 2; ++i)
#pragma unroll
        for (int q = 0; q < 3; ++q)
          acc[i][q] = __builtin_amdgcn_mfma_f32_16x16x32_bf16(wf[i][q][kt], bf, acc[i][q], 0, 0, 0);
    }

#pragma unroll
    for (int i = 0; i < 2; ++i) {
      int byte8n = gi_byte(bl, 32 * (32 + w + 8 * i) + 8 * kg);
      ushort4_ gv = *(const ushort4_*)(gtile + byte8n);
#pragma unroll
      for (int r = 0; r < 4; ++r) {
        float rr = __builtin_amdgcn_rcpf(1.f + __expf(-acc[i][0][r]));
        float zz = __builtin_amdgcn_rcpf(1.f + __expf(-acc[i][1][r]));
        float y = b2f(gv[r]) + rr * acc[i][2][r];
        float nn = 1.f - 2.f * __builtin_amdgcn_rcpf(1.f + __expf(2.f * y));
        hreg[i][r] = (1.f - zz) * nn + zz * hreg[i][r];
      }
      int byte0 = (bl * 512 + ((w + 8 * i) * 16 + kg * 4) * 2) ^ s16;
      uint2_ hv;
      hv.x = (unsigned)f2b(hreg[i][0]) | ((unsigned)f2b(hreg[i][1]) << 16);
      hv.y = (unsigned)f2b(hreg[i][2]) | ((unsigned)f2b(hreg[i][3]) << 16);
      *(uint2_*)(smem + 98304 + nxt * 8192 + byte0) = hv;
    }
  }

#pragma unroll
  for (int i = 0; i < 2; ++i) {
    float4_ v = {hreg[i][0], hreg[i][1], hreg[i][2], hreg[i][3]};
    *(float4_*)&out[(size_t)(b0 + bl) * HID + (w + 8 * i) * 16 + kg * 4] = v;
  }
}

extern "C" void kernel_launch(void* const* d_in, const int* in_sizes, int n_in,
                              void* d_out, int out_size, void* d_ws, size_t ws_size,
                              hipStream_t stream) {
  const int* x = (const int*)d_in[0];
  const float* emb = (const float*)d_in[1];
  const float* Wih = (const float*)d_in[2];
  const float* Whh = (const float*)d_in[3];
  const float* bih = (const float*)d_in[4];
  const float* bhh = (const float*)d_in[5];
  float* out = (float*)d_out;

  char* ws = (char*)d_ws;
  ushort_t* emb16 = (ushort_t*)ws;                 // 8,192,000 B
  ushort_t* Wih16 = (ushort_t*)(ws + 8192000);     //   196,608 B
  ushort_t* Whh16 = (ushort_t*)(ws + 8388608);     //   393,216 B
  unsigned* flags = (unsigned*)(ws + FLAGS_OFF);   //       512 B (2 phases x 64 words)
  char* gi = ws + GI_OFF;                          // 201,326,592 B, write-once/launch

  cvt_bf16_k<<<1024, 256, 0, stream>>>(emb, emb16, (VOCAB * EMB) / 4);
  cvt_bf16_k<<<96, 256, 0, stream>>>(Wih, Wih16, (G3 * EMB) / 4);
  cvt_bf16_k<<<192, 256, 0, stream>>>(Whh, Whh16, (G3 * HID) / 4);
  hipMemsetAsync(ws + FLAGS_OFF, 0, 512, stream);
  gru_fused<<<256, 512, 0, stream>>>(x, emb16, Wih16, Whh16, bih, bhh, gi, flags, out, 0);
  gru_fused<<<256, 512, 0, stream>>>(x, emb16, Wih16, Whh16, bih, bhh, gi, flags, out, 1);
}